// Round 9
// baseline (550.477 us; speedup 1.0000x reference)
//
#include <hip/hip_runtime.h>
#include <hip/hip_cooperative_groups.h>
#include <hip/hip_bf16.h>
#include <math.h>

namespace cg = cooperative_groups;

#define NTOT  8192
#define DIM   512
#define BATCH (NTOT/2)
#define TEMP_INV 5.0f   // 1/0.2
#define TTILE 64
#define NBLK  (TTILE*(TTILE+1)/2)   // 2080 upper-triangle tiles
#define KCH   16                    // gram split-K slices (512 samples each)

typedef __attribute__((ext_vector_type(8))) short bf16x8;
typedef __attribute__((ext_vector_type(4))) float f32x4;

// column-major triangle decode: t = bj*(bj+1)/2 + bi, bi <= bj.
__device__ __forceinline__ void decode_tile(int t, int& bi, int& bj)
{
    int b = (int)((sqrtf(8.0f * (float)t + 1.0f) - 1.0f) * 0.5f);
    while ((b + 1) * (b + 2) / 2 <= t) ++b;
    while (b * (b + 1) / 2 > t)       --b;
    bj = b;
    bi = t - b * (b + 1) / 2;
}

__device__ __forceinline__ unsigned int pack_bf16_2(float a, float b)
{
    __hip_bfloat16 ha = __float2bfloat16(a), hb = __float2bfloat16(b);
    unsigned short ua, ub;
    __builtin_memcpy(&ua, &ha, 2); __builtin_memcpy(&ub, &hb, 2);
    return (unsigned int)ua | ((unsigned int)ub << 16);
}
__device__ __forceinline__ float us2f(unsigned short u)
{
    __hip_bfloat16 h; __builtin_memcpy(&h, &u, 2);
    return __bfloat162float(h);
}

// 128x128 bf16 MFMA tile, K=512, BK=64, frag-order LDS (validated R6 structure).
__device__ __forceinline__ void gemm_tile(const __hip_bfloat16* __restrict__ A0, size_t sA,
                                          const __hip_bfloat16* __restrict__ B0, size_t sB,
                                          unsigned short* Asm, unsigned short* Bsm,
                                          int wave, int lane, f32x4 (&acc)[4][4])
{
    const int f_l = lane & 15, q_l = lane >> 4;
    const int wr = wave >> 1, wc = wave & 1;
    auto issue = [&](int k0) {
        #pragma unroll
        for (int s4 = 0; s4 < 4; ++s4) {
            const int seg = wave * 4 + s4, rowseg = seg >> 1, kh = seg & 1;
            const int gk  = k0 + kh * 32 + q_l * 8;
            const __hip_bfloat16* ga = A0 + (size_t)(rowseg * 16 + f_l) * sA + gk;
            const __hip_bfloat16* gb = B0 + (size_t)(rowseg * 16 + f_l) * sB + gk;
            __builtin_amdgcn_global_load_lds(
                (const __attribute__((address_space(1))) unsigned int*)ga,
                (__attribute__((address_space(3))) unsigned int*)(Asm + seg * 512 + lane * 8), 16, 0, 0);
            __builtin_amdgcn_global_load_lds(
                (const __attribute__((address_space(1))) unsigned int*)gb,
                (__attribute__((address_space(3))) unsigned int*)(Bsm + seg * 512 + lane * 8), 16, 0, 0);
        }
    };
    #pragma unroll
    for (int r = 0; r < 4; ++r)
        #pragma unroll
        for (int c = 0; c < 4; ++c) acc[r][c] = (f32x4){0.f, 0.f, 0.f, 0.f};
    issue(0);
    for (int ki = 0; ki < 8; ++ki) {
        __syncthreads();                        // loads(ki) landed
        bf16x8 af[4][2], bfr[4][2];
        #pragma unroll
        for (int r = 0; r < 4; ++r)
            #pragma unroll
            for (int h = 0; h < 2; ++h)
                af[r][h] = *(const bf16x8*)(Asm + ((wr*4+r)*2+h)*512 + lane*8);
        #pragma unroll
        for (int c = 0; c < 4; ++c)
            #pragma unroll
            for (int h = 0; h < 2; ++h)
                bfr[c][h] = *(const bf16x8*)(Bsm + ((wc*4+c)*2+h)*512 + lane*8);
        __syncthreads();                        // reads done -> buffer free
        if (ki < 7) issue((ki + 1) * 64);
        #pragma unroll
        for (int h = 0; h < 2; ++h)
            #pragma unroll
            for (int r = 0; r < 4; ++r)
                #pragma unroll
                for (int c = 0; c < 4; ++c)
                    acc[r][c] = __builtin_amdgcn_mfma_f32_16x16x32_bf16(af[r][h], bfr[c][h], acc[r][c], 0,0,0);
    }
}

__global__ __launch_bounds__(256, 4)
void mega_k(const float* __restrict__ z, const int* __restrict__ labels,
            __hip_bfloat16* __restrict__ zn, __hip_bfloat16* __restrict__ znT,
            float* __restrict__ Spart, float* __restrict__ S,
            float* __restrict__ rowsum, float* __restrict__ q,
            double* __restrict__ accs, unsigned int* __restrict__ ctr,
            __hip_bfloat16* __restrict__ Gbf, float* __restrict__ Gpart,
            float* __restrict__ out)
{
    __shared__ __align__(16) char ldsraw[32832];
    __shared__ int steal;
    unsigned short* Asm = (unsigned short*)ldsraw;          // 16 KB
    unsigned short* Bsm = Asm + 8192;                       // 16 KB
    float* redbuf = (float*)(Bsm + 8192);                   // 32 B
    const int tid = threadIdx.x, wave = tid >> 6, lane = tid & 63;
    const int nb = gridDim.x, bid = blockIdx.x;
    cg::grid_group grid = cg::this_grid();

    // ---- phase 1: normalize -> zn(bf16); LDS transpose -> znT; Spart col-sums ----
    {
        unsigned short (*tile)[516] = (unsigned short(*)[516])ldsraw;
        const int half = lane >> 5, l32 = lane & 31;
        for (int g = bid; g < NTOT / 8; g += nb) {
            const int r0 = g * 8;
            const int lrow = wave * 2 + half;
            const int row  = r0 + lrow;
            const float4* zr = (const float4*)(z + (size_t)row * DIM + l32 * 16);
            const float4 v0 = zr[0], v1 = zr[1], v2 = zr[2], v3 = zr[3];
            float ss = v0.x*v0.x+v0.y*v0.y+v0.z*v0.z+v0.w*v0.w
                     + v1.x*v1.x+v1.y*v1.y+v1.z*v1.z+v1.w*v1.w
                     + v2.x*v2.x+v2.y*v2.y+v2.z*v2.z+v2.w*v2.w
                     + v3.x*v3.x+v3.y*v3.y+v3.z*v3.z+v3.w*v3.w;
            #pragma unroll
            for (int off = 1; off < 32; off <<= 1) ss += __shfl_xor(ss, off);
            const float inv = 1.0f / fmaxf(sqrtf(ss), 1e-12f);
            uint4 oa, ob;
            oa.x = pack_bf16_2(v0.x*inv, v0.y*inv); oa.y = pack_bf16_2(v0.z*inv, v0.w*inv);
            oa.z = pack_bf16_2(v1.x*inv, v1.y*inv); oa.w = pack_bf16_2(v1.z*inv, v1.w*inv);
            ob.x = pack_bf16_2(v2.x*inv, v2.y*inv); ob.y = pack_bf16_2(v2.z*inv, v2.w*inv);
            ob.z = pack_bf16_2(v3.x*inv, v3.y*inv); ob.w = pack_bf16_2(v3.z*inv, v3.w*inv);
            uint4* gdst = (uint4*)(zn + (size_t)row * DIM + l32 * 16);
            gdst[0] = oa; gdst[1] = ob;
            uint4* ldst = (uint4*)&tile[lrow][l32 * 16];
            ldst[0] = oa; ldst[1] = ob;
            __syncthreads();
            #pragma unroll
            for (int dv = 0; dv < 2; ++dv) {
                const int d = tid + dv * 256;
                float s = 0.f; bf16x8 w;
                #pragma unroll
                for (int e = 0; e < 8; ++e) {
                    const unsigned short u = tile[e][d];
                    w[e] = (short)u; s += us2f(u);
                }
                *(bf16x8*)(znT + (size_t)d * NTOT + r0) = w;
                atomicAdd(&Spart[(bid & 7) * DIM + d], s);
            }
            __syncthreads();
        }
    }
    grid.sync();

    // ---- phase 3: Gram partial slices (plain stores, no atomics) ----
    for (int w = bid; w < 16 * KCH; w += nb) {
        const int pos = w & 15, kc = w >> 4;
        const int a0 = (pos >> 2) * 128, b0 = (pos & 3) * 128;
        f32x4 acc[4][4];
        gemm_tile(znT + (size_t)a0 * NTOT + kc * 512, NTOT,
                  znT + (size_t)b0 * NTOT + kc * 512, NTOT, Asm, Bsm, wave, lane, acc);
        const int f_l = lane & 15, q_l = lane >> 4, wr = wave >> 1, wc = wave & 1;
        float* dst = Gpart + (size_t)kc * DIM * DIM;
        #pragma unroll
        for (int r = 0; r < 4; ++r)
            #pragma unroll
            for (int c = 0; c < 4; ++c)
                #pragma unroll
                for (int u = 0; u < 4; ++u)
                    dst[(size_t)(a0 + wr*64 + r*16 + q_l*4 + u) * DIM
                        + b0 + wc*64 + c*16 + f_l] = acc[r][c][u];
    }
    grid.sync();

    // ---- phase 5: sum slices -> bf16 G ; finalize S ----
    for (int idx = bid * 256 + tid; idx < DIM * DIM / 4; idx += nb * 256) {
        float4 s = {0.f, 0.f, 0.f, 0.f};
        #pragma unroll
        for (int kc = 0; kc < KCH; ++kc) {
            const float4 g = ((const float4*)Gpart)[(size_t)kc * (DIM * DIM / 4) + idx];
            s.x += g.x; s.y += g.y; s.z += g.z; s.w += g.w;
        }
        uint2 o; o.x = pack_bf16_2(s.x, s.y); o.y = pack_bf16_2(s.z, s.w);
        ((uint2*)Gbf)[idx] = o;
    }
    for (int d = bid * 256 + tid; d < DIM; d += nb * 256) {
        float s = 0.f;
        #pragma unroll
        for (int sl = 0; sl < 8; ++sl) s += Spart[sl * DIM + d];
        S[d] = s;
    }
    grid.sync();

    // ---- phase 7: Y-tile = Zn*G; epilogue reduces q_i, rowsum_i ----
    for (int w = bid; w < 256; w += nb) {
        const int C0 = (w & 3) * 128, R0 = (w >> 2) * 128;
        f32x4 acc[4][4];
        gemm_tile(zn + (size_t)R0 * DIM, DIM, Gbf + (size_t)C0 * DIM, DIM,
                  Asm, Bsm, wave, lane, acc);
        const int f_l = lane & 15, q_l = lane >> 4, wr = wave >> 1, wc = wave & 1;
        float Sn[4];
        #pragma unroll
        for (int c = 0; c < 4; ++c) Sn[c] = S[C0 + wc*64 + c*16 + f_l];
        #pragma unroll
        for (int r = 0; r < 4; ++r) {
            float qp[4] = {0,0,0,0}, rp[4] = {0,0,0,0};
            #pragma unroll
            for (int c = 0; c < 4; ++c) {
                const int n = C0 + wc*64 + c*16 + f_l;
                #pragma unroll
                for (int u = 0; u < 4; ++u) {
                    const int i = R0 + wr*64 + r*16 + q_l*4 + u;
                    const float wv = __bfloat162float(zn[(size_t)i * DIM + n]);
                    qp[u] += acc[r][c][u] * wv;
                    rp[u] += wv * Sn[c];
                }
            }
            #pragma unroll
            for (int off = 1; off < 16; off <<= 1) {
                #pragma unroll
                for (int u = 0; u < 4; ++u) {
                    qp[u] += __shfl_xor(qp[u], off);
                    rp[u] += __shfl_xor(rp[u], off);
                }
            }
            if (f_l == 0) {
                #pragma unroll
                for (int u = 0; u < 4; ++u) {
                    const int i = R0 + wr*64 + r*16 + q_l*4 + u;
                    atomicAdd(&q[i], qp[u]);
                    atomicAdd(&rowsum[i], rp[u]);
                }
            }
        }
    }
    grid.sync();

    // ---- phase 9: sim triangle pass via work stealing; neg + thin pos epilogue ----
    for (;;) {
        if (tid == 0) steal = (int)atomicAdd(ctr, 1u);
        __syncthreads();
        const int t = steal;
        __syncthreads();
        if (t >= NBLK) break;
        int bi, bj; decode_tile(t, bi, bj);
        const int R0 = bi * 128, C0 = bj * 128;
        f32x4 acc[4][4];
        gemm_tile(zn + (size_t)R0 * DIM, DIM, zn + (size_t)C0 * DIM, DIM,
                  Asm, Bsm, wave, lane, acc);
        const int f_l = lane & 15, q_l = lane >> 4, wr = wave >> 1, wc = wave & 1;

        int labj[4]; float muj[4], isj[4];
        #pragma unroll
        for (int c = 0; c < 4; ++c) {
            const int j = C0 + wc*64 + c*16 + f_l;
            labj[c] = labels[j];
            const float rs = rowsum[j], qq = q[j];
            const float mean = rs * (1.0f / NTOT);
            const float var  = (qq - rs * mean) * (1.0f / (NTOT - 1));
            muj[c] = 1.0f - mean;
            isj[c] = 1.0f / (2.0f * var);
        }
        float local = 0.f;
        #pragma unroll
        for (int r = 0; r < 4; ++r) {
            const int ib = R0 + wr*64 + r*16 + q_l*4;
            int li[4]; float mi[4], vi[4];
            #pragma unroll
            for (int u = 0; u < 4; ++u) {
                li[u] = labels[ib + u];
                const float rs = rowsum[ib + u], qq = q[ib + u];
                const float mean = rs * (1.0f / NTOT);
                const float var  = (qq - rs * mean) * (1.0f / (NTOT - 1));
                mi[u] = 1.0f - mean;
                vi[u] = 1.0f / (2.0f * var);
            }
            #pragma unroll
            for (int u = 0; u < 4; ++u) {
                #pragma unroll
                for (int c = 0; c < 4; ++c) {
                    const float s  = acc[r][c][u];
                    const float d  = 1.0f - s;
                    const float dj = d - muj[c];
                    float e = __expf(s * TEMP_INV + dj * dj * isj[c]);
                    if (bi != bj) {                    // wave-uniform
                        const float di = d - mi[u];
                        e += __expf(s * TEMP_INV + di * di * vi[u]);
                    }
                    local += (li[u] != labj[c]) ? e : 0.f;
                }
            }
        }
        // thin pos epilogue: only tiles bj==bi+32 hold pairs (i, i+4096) on their diagonal
        float posl = 0.f;
        if (bj == bi + 32 && wr == wc) {
            #pragma unroll
            for (int r = 0; r < 4; ++r)
                #pragma unroll
                for (int u = 0; u < 4; ++u)
                    if (f_l == q_l * 4 + u) {
                        const int ig = R0 + wr*64 + r*16 + f_l;
                        if (labels[ig] == labels[ig + BATCH])
                            posl += __expf(acc[r][r][u] * TEMP_INV);
                    }
        }
        #pragma unroll
        for (int off = 1; off < 64; off <<= 1) {
            local += __shfl_xor(local, off);
            posl  += __shfl_xor(posl, off);
        }
        if (lane == 0) { redbuf[wave] = local; redbuf[4 + wave] = posl; }
        __syncthreads();
        if (tid == 0) {
            atomicAdd(&accs[0], (double)(redbuf[0] + redbuf[1] + redbuf[2] + redbuf[3]));
            const double p = (double)(redbuf[4] + redbuf[5] + redbuf[6] + redbuf[7]);
            if (p != 0.0) atomicAdd(&accs[1], p);
        }
        __syncthreads();
    }
    grid.sync();

    if (bid == 0 && tid == 0) {
        const double neg = ((volatile double*)accs)[0];
        const double pos = ((volatile double*)accs)[1];
        out[0] = (float)(-log(pos / (pos + neg)));
    }
}

extern "C" void kernel_launch(void* const* d_in, const int* in_sizes, int n_in,
                              void* d_out, int out_size, void* d_ws, size_t ws_size,
                              hipStream_t stream)
{
    const float* z      = (const float*)d_in[0];
    const int*   labels = (const int*)d_in[1];
    float* out = (float*)d_out;

    char* ws = (char*)d_ws;
    __hip_bfloat16* zn  = (__hip_bfloat16*)ws;                       // 8 MiB
    const size_t ZN_BYTES = (size_t)NTOT * DIM * 2;
    __hip_bfloat16* znT = (__hip_bfloat16*)(ws + ZN_BYTES);          // 8 MiB
    char* p = ws + 2 * ZN_BYTES;
    float*        Spart  = (float*)p;        p += 8 * DIM * sizeof(float);    // 16 KB
    float*        S      = (float*)p;        p += DIM * sizeof(float);        // 2 KB
    float*        rowsum = (float*)p;        p += NTOT * sizeof(float);       // 32 KB
    float*        q      = (float*)p;        p += NTOT * sizeof(float);       // 32 KB
    double*       accs   = (double*)p;       p += 2 * sizeof(double);         // 16 B
    unsigned int* ctr    = (unsigned int*)p; p += 16;                         // 16 B
    const size_t ZERO_BYTES = (size_t)(p - (char*)Spart);
    __hip_bfloat16* Gbf  = (__hip_bfloat16*)p; p += (size_t)DIM * DIM * 2;    // 512 KB
    p = (char*)(((uintptr_t)p + 255) & ~(uintptr_t)255);
    float*        Gpart  = (float*)p;        // KCH MB (16 MB), plain-stored, no zeroing

    hipMemsetAsync(Spart, 0, ZERO_BYTES, stream);

    int maxB = 0;
    hipOccupancyMaxActiveBlocksPerMultiprocessor(&maxB, mega_k, 256, 0);
    if (maxB < 1) maxB = 1;
    int grid = maxB * 256;
    if (grid > 1024) grid = 1024;

    void* kargs[] = { (void*)&z, (void*)&labels, (void*)&zn, (void*)&znT,
                      (void*)&Spart, (void*)&S, (void*)&rowsum, (void*)&q,
                      (void*)&accs, (void*)&ctr, (void*)&Gbf, (void*)&Gpart,
                      (void*)&out };
    hipLaunchCooperativeKernel(mega_k, dim3(grid), dim3(256), kargs, 0, stream);
}